// Round 14
// baseline (90.793 us; speedup 1.0000x reference)
//
#include <hip/hip_runtime.h>

#define NUM_NODES 100000
#define INPUT_DIM 256
#define NUM_BAGS  2048
#define BAG_SIZE  64
#define N_EDGES   3200000
#define NQUAD     (N_EDGES / 4)     // 800000
#define NBKT      391               // ceil(100000/256) buckets of 256 nodes
#define BLK_A     256               // pack/scatter blocks
#define QPB       (NQUAD / BLK_A)   // 3125 quads per block (exact)

typedef unsigned int u32;

// ---------------------------------------------------------------------------
// A: pack + per-block bucket counts.
//   word = (src << 15) | bf15(nw[nbr])    (weights in [0,1) -> sign bit 0)
//   bucket(word) = word >> 23  (= src >> 8, 0..390)
// Counts go to cnt[bucket][blk] (bucket-major) for the scan.
__global__ void __launch_bounds__(1024)
pack_count(const int* __restrict__ edge_src, const int* __restrict__ edge_nbr,
           const float* __restrict__ nw, u32* __restrict__ packed,
           u32* __restrict__ cnt) {
    __shared__ u32 lcnt[NBKT];
    const int blk = blockIdx.x;
    const int tid = threadIdx.x;
    for (int j = tid; j < NBKT; j += 1024) lcnt[j] = 0;
    __syncthreads();

    const int lo = blk * QPB, hi = lo + QPB;
    for (int q = lo + tid; q < hi; q += 1024) {
        const int4 s4 = ((const int4*)edge_src)[q];
        const int4 n4 = ((const int4*)edge_nbr)[q];
#define PACK(S, N)  (((u32)(S) << 15) |                                     \
                     (((__float_as_uint(nw[(N)]) + 0x8000u) >> 16) & 0x7FFFu))
        uint4 o;
        o.x = PACK(s4.x, n4.x);
        o.y = PACK(s4.y, n4.y);
        o.z = PACK(s4.z, n4.z);
        o.w = PACK(s4.w, n4.w);
#undef PACK
        ((uint4*)packed)[q] = o;
        atomicAdd(&lcnt[o.x >> 23], 1u);
        atomicAdd(&lcnt[o.y >> 23], 1u);
        atomicAdd(&lcnt[o.z >> 23], 1u);
        atomicAdd(&lcnt[o.w >> 23], 1u);
    }
    __syncthreads();
    for (int j = tid; j < NBKT; j += 1024) cnt[j * BLK_A + blk] = lcnt[j];
}

// ---------------------------------------------------------------------------
// B1: tot[b] = sum_blk cnt[b][blk]
__global__ void __launch_bounds__(256)
bucket_tot(const u32* __restrict__ cnt, u32* __restrict__ tot) {
    __shared__ u32 s[256];
    const int b = blockIdx.x;
    s[threadIdx.x] = cnt[b * BLK_A + threadIdx.x];
    __syncthreads();
    for (int off = 128; off >= 1; off >>= 1) {
        if (threadIdx.x < off) s[threadIdx.x] += s[threadIdx.x + off];
        __syncthreads();
    }
    if (threadIdx.x == 0) tot[b] = s[0];
}

// B2: gofs[b][blk] = (sum_{b'<b} tot[b']) + (sum_{blk'<blk} cnt[b][blk'])
__global__ void __launch_bounds__(256)
bucket_ofs(const u32* __restrict__ cnt, const u32* __restrict__ tot,
           u32* __restrict__ gofs) {
    __shared__ u32 s[256];
    __shared__ u32 pb[256];
    const int b   = blockIdx.x;
    const int tid = threadIdx.x;

    // base[b] = prefix over tot
    u32 part = 0;
    if (tid < b) part += tot[tid];
    if (tid + 256 < b) part += tot[tid + 256];
    pb[tid] = part;
    __syncthreads();
    for (int off = 128; off >= 1; off >>= 1) {
        if (tid < off) pb[tid] += pb[tid + off];
        __syncthreads();
    }
    const u32 base = pb[0];

    // exclusive scan of the block's row
    const u32 v = cnt[b * BLK_A + tid];
    s[tid] = v;
    for (int off = 1; off < 256; off <<= 1) {
        __syncthreads();
        const u32 t = (tid >= off) ? s[tid - off] : 0u;
        __syncthreads();
        s[tid] += t;
    }
    gofs[b * BLK_A + tid] = base + s[tid] - v;   // exclusive
}

// ---------------------------------------------------------------------------
// C: scatter packed words to bucket-sorted positions. cursor[b] starts at
// this block's global offset; 1 LDS atomic + 1 (mostly-merging) 4B store/edge.
__global__ void __launch_bounds__(1024)
scatter(const u32* __restrict__ packed, const u32* __restrict__ gofs,
        u32* __restrict__ sorted) {
    __shared__ u32 cursor[NBKT];
    const int blk = blockIdx.x;
    const int tid = threadIdx.x;
    for (int j = tid; j < NBKT; j += 1024) cursor[j] = gofs[j * BLK_A + blk];
    __syncthreads();

    const int lo = blk * QPB, hi = lo + QPB;
    for (int q = lo + tid; q < hi; q += 1024) {
        const uint4 o = ((const uint4*)packed)[q];
#define PUT(W) { const u32 pos = atomicAdd(&cursor[(W) >> 23], 1u); sorted[pos] = (W); }
        PUT(o.x) PUT(o.y) PUT(o.z) PUT(o.w)
#undef PUT
    }
}

// ---------------------------------------------------------------------------
// D: per-bucket histogram. Block b owns nodes [b*256, b*256+256) exclusively:
// reads its contiguous sorted range once, 256-float LDS hist, every lane
// useful, writes nbr_sum directly with the (sum>0 ? sum : 1.0) fold.
__global__ void __launch_bounds__(512)
bucket_hist(const u32* __restrict__ sorted, const u32* __restrict__ gofs,
            float* __restrict__ nbr_sum) {
    __shared__ float hist[256];
    const int b   = blockIdx.x;
    const int tid = threadIdx.x;
    if (tid < 256) hist[tid] = 0.f;
    __syncthreads();

    const u32 lo = gofs[b * BLK_A + 0];
    const u32 hi = (b + 1 < NBKT) ? gofs[(b + 1) * BLK_A + 0] : (u32)N_EDGES;
    for (u32 i = lo + tid; i < hi; i += 512) {
        const u32 w = sorted[i];
        atomicAdd(&hist[(w >> 15) & 255u], __uint_as_float((w & 0x7FFFu) << 16));
    }
    __syncthreads();

    if (tid < 256) {
        const int n = b * 256 + tid;
        if (n < NUM_NODES) {
            const float s = hist[tid];
            nbr_sum[n] = s > 0.f ? s : 1.0f;
        }
    }
}

// ---------------------------------------------------------------------------
// E: h[n] = theta . x[n] — dense coalesced GEMV (~88% HBM peak).
__global__ void __launch_bounds__(256)
gemv_h(const float* __restrict__ x, const float* __restrict__ theta,
       float* __restrict__ h) {
    const int lane = threadIdx.x & 63;
    const int wave = threadIdx.x >> 6;
    const float4 tw = *reinterpret_cast<const float4*>(&theta[lane * 4]);
    const int stride = gridDim.x * 4;
    for (int row = blockIdx.x * 4 + wave; row < NUM_NODES; row += stride) {
        const float4 xv =
            *reinterpret_cast<const float4*>(&x[(size_t)row * INPUT_DIM + lane * 4]);
        float d = xv.x * tw.x + xv.y * tw.y + xv.z * tw.z + xv.w * tw.w;
        #pragma unroll
        for (int off = 32; off >= 1; off >>= 1)
            d += __shfl_xor(d, off);
        if (lane == 0) h[row] = d;
    }
}

// F: out[bag] = sum_item h[idx] * nbr_sum[idx] * alpha
__global__ void __launch_bounds__(256)
bag_final(const int* __restrict__ bags, const float* __restrict__ alpha,
          const float* __restrict__ h, const float* __restrict__ ns,
          float* __restrict__ out) {
    const int bag  = blockIdx.x * 4 + (threadIdx.x >> 6);
    const int lane = threadIdx.x & 63;
    const int idx  = bags[bag * BAG_SIZE + lane];
    float v = h[idx] * ns[idx] * alpha[bag * BAG_SIZE + lane];
    #pragma unroll
    for (int off = 32; off >= 1; off >>= 1)
        v += __shfl_xor(v, off);
    if (lane == 0) out[bag] = v;
}

// Tiny-ws fallback: plain device atomics.
__global__ void __launch_bounds__(256)
edge_atomic(const int* __restrict__ edge_src, const int* __restrict__ edge_nbr,
            const float* __restrict__ nw, float* __restrict__ nbr_sum) {
    const int t = blockIdx.x * blockDim.x + threadIdx.x;
    const int4 s4 = ((const int4*)edge_src)[t];
    const int4 n4 = ((const int4*)edge_nbr)[t];
    atomicAdd(&nbr_sum[s4.x], nw[n4.x]);
    atomicAdd(&nbr_sum[s4.y], nw[n4.y]);
    atomicAdd(&nbr_sum[s4.z], nw[n4.z]);
    atomicAdd(&nbr_sum[s4.w], nw[n4.w]);
}

__global__ void __launch_bounds__(256)
fixup_nosum(float* __restrict__ nbr_sum) {
    const int i = blockIdx.x * 256 + threadIdx.x;
    if (i < NUM_NODES && nbr_sum[i] == 0.f) nbr_sum[i] = 1.0f;
}

extern "C" void kernel_launch(void* const* d_in, const int* in_sizes, int n_in,
                              void* d_out, int out_size, void* d_ws, size_t ws_size,
                              hipStream_t stream) {
    const float* x            = (const float*)d_in[0];
    const int*   bags         = (const int*)d_in[1];
    const float* alpha        = (const float*)d_in[2];
    const int*   edge_src     = (const int*)d_in[3];
    const int*   edge_nbr     = (const int*)d_in[4];
    const float* node_weights = (const float*)d_in[5];
    const float* theta        = (const float*)d_in[6];
    float*       out          = (float*)d_out;

    // ws: packed[3.2M] | sorted[3.2M] | cnt[391*256] | gofs[391*256] |
    //     tot[391] | nbr_sum[100K] | h[100K]    (~27.5 MB; no memsets needed)
    const size_t need_full =
        ((size_t)N_EDGES * 2 + 2 * (size_t)NBKT * BLK_A + NBKT
         + 2 * (size_t)NUM_NODES) * 4;

    if (ws_size >= need_full) {
        u32*   packed  = (u32*)d_ws;
        u32*   sorted  = packed + N_EDGES;
        u32*   cnt     = sorted + N_EDGES;
        u32*   gofs    = cnt + (size_t)NBKT * BLK_A;
        u32*   tot     = gofs + (size_t)NBKT * BLK_A;
        float* nbr_sum = (float*)(tot + NBKT);
        float* h       = nbr_sum + NUM_NODES;

        pack_count<<<BLK_A, 1024, 0, stream>>>(edge_src, edge_nbr,
                                               node_weights, packed, cnt);
        bucket_tot<<<NBKT, 256, 0, stream>>>(cnt, tot);
        bucket_ofs<<<NBKT, 256, 0, stream>>>(cnt, tot, gofs);
        scatter<<<BLK_A, 1024, 0, stream>>>(packed, gofs, sorted);
        bucket_hist<<<NBKT, 512, 0, stream>>>(sorted, gofs, nbr_sum);
        gemv_h<<<2048, 256, 0, stream>>>(x, theta, h);
        bag_final<<<NUM_BAGS / 4, 256, 0, stream>>>(bags, alpha, h, nbr_sum, out);
    } else {
        // Tiny-ws fallback: device atomics (needs 800 KB).
        float* nbr_sum = (float*)d_ws;
        float* h       = nbr_sum + NUM_NODES;
        hipMemsetAsync(nbr_sum, 0, (size_t)NUM_NODES * 4, stream);
        edge_atomic<<<(N_EDGES / 4) / 256, 256, 0, stream>>>(
            edge_src, edge_nbr, node_weights, nbr_sum);
        fixup_nosum<<<(NUM_NODES + 255) / 256, 256, 0, stream>>>(nbr_sum);
        gemv_h<<<2048, 256, 0, stream>>>(x, theta, h);
        bag_final<<<NUM_BAGS / 4, 256, 0, stream>>>(bags, alpha, h, nbr_sum, out);
    }
}

// Round 15
// 73.962 us; speedup vs baseline: 1.2276x; 1.2276x over previous
//
#include <hip/hip_runtime.h>

#define NUM_NODES 100000
#define INPUT_DIM 256
#define NUM_BAGS  2048
#define BAG_SIZE  64
#define N_EDGES   3200000
#define NQUAD     (N_EDGES / 4)   // 800000

// P=3 path: 130 KB dynamic LDS per block
#define NPP3      33334           // 3*33334 >= 100000; 133336 B <= 160 KB
#define NSL3      85              // grid = 3*85 = 255 <= 256 CUs
#define QPS3      9412            // ceil(800000/85)
// P=8 fallback path (R13): 50 KB static LDS
#define NPP8      12500
#define NSL8      32
#define QPS8      (NQUAD / NSL8)  // 25000

typedef unsigned int u32;
typedef float f4 __attribute__((ext_vector_type(4)));

// Pass A: pack (src, w) into one u32 per edge.
//   word = (src << 15) | bf15(nw[nbr])   (weights in [0,1) -> sign bit 0)
__global__ void __launch_bounds__(256)
pack_edges(const int* __restrict__ edge_src, const int* __restrict__ edge_nbr,
           const float* __restrict__ nw, u32* __restrict__ packed) {
    const int q = blockIdx.x * 256 + threadIdx.x;    // one quad / thread
    const int4 s4 = ((const int4*)edge_src)[q];
    const int4 n4 = ((const int4*)edge_nbr)[q];
#define PACK(S, N)  (((u32)(S) << 15) |                                     \
                     (((__float_as_uint(nw[(N)]) + 0x8000u) >> 16) & 0x7FFFu))
    uint4 o;
    o.x = PACK(s4.x, n4.x);
    o.y = PACK(s4.y, n4.y);
    o.z = PACK(s4.z, n4.z);
    o.w = PACK(s4.w, n4.w);
#undef PACK
    ((uint4*)packed)[q] = o;
}

// Pass B (main): P=3 partitioned hist, 130 KB dynamic LDS.
// Rescan = 3 x 12.8 MB = 38.4 MB total (the byte-cost model's lever).
__global__ void __launch_bounds__(1024)
hist3(const u32* __restrict__ packed, float* __restrict__ rep) {
    extern __shared__ float hist[];            // NPP3 floats
    const int p    = blockIdx.x / NSL3;        // 0..2
    const int b    = blockIdx.x % NSL3;        // 0..84
    const int base = p * NPP3;
    const int tid  = threadIdx.x;

    for (int j = tid; j < NPP3; j += 1024) hist[j] = 0.f;
    __syncthreads();

    const int lo = b * QPS3;
    const int hi = (lo + QPS3 < NQUAD) ? lo + QPS3 : NQUAD;
#define EDGE(W)                                                          \
        {                                                                \
            const u32 rel = ((W) >> 15) - (u32)base;                     \
            if (rel < (u32)NPP3)                                         \
                atomicAdd(&hist[rel],                                    \
                          __uint_as_float(((W) & 0x7FFFu) << 16));       \
        }
    for (int q = lo + tid; q < hi; q += 1024) {
        const uint4 a = ((const uint4*)packed)[q];
        EDGE(a.x) EDGE(a.y) EDGE(a.z) EDGE(a.w)
    }
#undef EDGE
    __syncthreads();

    const int nflush = (NUM_NODES - base < NPP3) ? NUM_NODES - base : NPP3;
    float* dst = rep + (size_t)b * NUM_NODES + base;
    for (int j = tid; j < nflush; j += 1024)
        __builtin_nontemporal_store(hist[j], &dst[j]);
}

// Pass B (fallback): R13's P=8 static-LDS hist, NSLICE=32.
__global__ void __launch_bounds__(1024)
hist_p(const u32* __restrict__ packed, float* __restrict__ rep) {
    __shared__ float hist[NPP8];
    const int i    = blockIdx.x;
    const int r    = i & 7;
    const int p    = (i >> 3) & 7;
    const int b    = r | ((i >> 6) << 3);      // 0..31
    const int base = p * NPP8;

    for (int j = threadIdx.x; j < NPP8 / 4; j += 1024)
        ((f4*)hist)[j] = (f4){0.f, 0.f, 0.f, 0.f};
    __syncthreads();

    const int lo = b * QPS8;
#define EDGE(W)                                                          \
        {                                                                \
            const u32 rel = ((W) >> 15) - (u32)base;                     \
            if (rel < (u32)NPP8)                                         \
                atomicAdd(&hist[rel],                                    \
                          __uint_as_float(((W) & 0x7FFFu) << 16));       \
        }
    for (int q = lo + (int)threadIdx.x; q < lo + QPS8; q += 1024) {
        const uint4 a = ((const uint4*)packed)[q];
        EDGE(a.x) EDGE(a.y) EDGE(a.z) EDGE(a.w)
    }
#undef EDGE
    __syncthreads();

    float* dst = rep + (size_t)b * NUM_NODES + base;
    for (int j = threadIdx.x; j < NPP8 / 4; j += 1024) {
        const f4 v = ((const f4*)hist)[j];
        __builtin_nontemporal_store(v, &((f4*)dst)[j]);
    }
}

// Fused: blocks [0,RED_BLK) reduce rep -> nbr_sum (with >0 ? : 1.0 fold);
// blocks [RED_BLK, RED_BLK+2048) dense GEMV. Independent streams.
#define RED_BLK 98   // ceil(25000 float4 / 256)
template <int NSL>
__global__ void __launch_bounds__(256)
gemv_reduce(const float* __restrict__ rep, float* __restrict__ nbr_sum,
            const float* __restrict__ x, const float* __restrict__ theta,
            float* __restrict__ h) {
    if (blockIdx.x < RED_BLK) {
        const int i = blockIdx.x * 256 + threadIdx.x;   // float4 index
        if (i >= NUM_NODES / 4) return;
        float4 a = make_float4(0.f, 0.f, 0.f, 0.f);
        #pragma unroll 5
        for (int r = 0; r < NSL; ++r) {
            const float4 v = ((const float4*)(rep + (size_t)r * NUM_NODES))[i];
            a.x += v.x; a.y += v.y; a.z += v.z; a.w += v.w;
        }
        float4 o;
        o.x = a.x > 0.f ? a.x : 1.0f;
        o.y = a.y > 0.f ? a.y : 1.0f;
        o.z = a.z > 0.f ? a.z : 1.0f;
        o.w = a.w > 0.f ? a.w : 1.0f;
        ((float4*)nbr_sum)[i] = o;
    } else {
        const int gb   = blockIdx.x - RED_BLK;          // 0..2047
        const int lane = threadIdx.x & 63;
        const int wave = threadIdx.x >> 6;
        const float4 tw = *reinterpret_cast<const float4*>(&theta[lane * 4]);
        for (int row = gb * 4 + wave; row < NUM_NODES; row += 2048 * 4) {
            const float4 xv =
                *reinterpret_cast<const float4*>(&x[(size_t)row * INPUT_DIM + lane * 4]);
            float d = xv.x * tw.x + xv.y * tw.y + xv.z * tw.z + xv.w * tw.w;
            #pragma unroll
            for (int off = 32; off >= 1; off >>= 1)
                d += __shfl_xor(d, off);
            if (lane == 0) h[row] = d;
        }
    }
}

// Final: out[bag] = sum_item h[idx] * nbr_sum[idx] * alpha
__global__ void __launch_bounds__(256)
bag_final(const int* __restrict__ bags, const float* __restrict__ alpha,
          const float* __restrict__ h, const float* __restrict__ ns,
          float* __restrict__ out) {
    const int bag  = blockIdx.x * 4 + (threadIdx.x >> 6);
    const int lane = threadIdx.x & 63;
    const int idx  = bags[bag * BAG_SIZE + lane];
    float v = h[idx] * ns[idx] * alpha[bag * BAG_SIZE + lane];
    #pragma unroll
    for (int off = 32; off >= 1; off >>= 1)
        v += __shfl_xor(v, off);
    if (lane == 0) out[bag] = v;
}

// Tiny-ws fallback: plain device atomics.
__global__ void __launch_bounds__(256)
edge_atomic(const int* __restrict__ edge_src, const int* __restrict__ edge_nbr,
            const float* __restrict__ nw, float* __restrict__ nbr_sum) {
    const int t = blockIdx.x * blockDim.x + threadIdx.x;
    const int4 s4 = ((const int4*)edge_src)[t];
    const int4 n4 = ((const int4*)edge_nbr)[t];
    atomicAdd(&nbr_sum[s4.x], nw[n4.x]);
    atomicAdd(&nbr_sum[s4.y], nw[n4.y]);
    atomicAdd(&nbr_sum[s4.z], nw[n4.z]);
    atomicAdd(&nbr_sum[s4.w], nw[n4.w]);
}

__global__ void __launch_bounds__(256)
fixup_nosum(float* __restrict__ nbr_sum) {
    const int i = blockIdx.x * 256 + threadIdx.x;
    if (i < NUM_NODES && nbr_sum[i] == 0.f) nbr_sum[i] = 1.0f;
}

__global__ void __launch_bounds__(256)
gemv_h(const float* __restrict__ x, const float* __restrict__ theta,
       float* __restrict__ h) {
    const int lane = threadIdx.x & 63;
    const int wave = threadIdx.x >> 6;
    const float4 tw = *reinterpret_cast<const float4*>(&theta[lane * 4]);
    const int stride = gridDim.x * 4;
    for (int row = blockIdx.x * 4 + wave; row < NUM_NODES; row += stride) {
        const float4 xv =
            *reinterpret_cast<const float4*>(&x[(size_t)row * INPUT_DIM + lane * 4]);
        float d = xv.x * tw.x + xv.y * tw.y + xv.z * tw.z + xv.w * tw.w;
        #pragma unroll
        for (int off = 32; off >= 1; off >>= 1)
            d += __shfl_xor(d, off);
        if (lane == 0) h[row] = d;
    }
}

extern "C" void kernel_launch(void* const* d_in, const int* in_sizes, int n_in,
                              void* d_out, int out_size, void* d_ws, size_t ws_size,
                              hipStream_t stream) {
    const float* x            = (const float*)d_in[0];
    const int*   bags         = (const int*)d_in[1];
    const float* alpha        = (const float*)d_in[2];
    const int*   edge_src     = (const int*)d_in[3];
    const int*   edge_nbr     = (const int*)d_in[4];
    const float* node_weights = (const float*)d_in[5];
    const float* theta        = (const float*)d_in[6];
    float*       out          = (float*)d_out;

    const size_t need3 =
        ((size_t)N_EDGES + (size_t)NSL3 * NUM_NODES + 2 * (size_t)NUM_NODES) * 4;
    const size_t need8 =
        ((size_t)N_EDGES + (size_t)NSL8 * NUM_NODES + 2 * (size_t)NUM_NODES) * 4;

    const hipError_t attr_ok = hipFuncSetAttribute(
        (const void*)hist3, hipFuncAttributeMaxDynamicSharedMemorySize,
        NPP3 * (int)sizeof(float));

    if (attr_ok == hipSuccess && ws_size >= need3) {
        u32*   packed  = (u32*)d_ws;
        float* rep     = (float*)d_ws + N_EDGES;
        float* nbr_sum = rep + (size_t)NSL3 * NUM_NODES;
        float* h       = nbr_sum + NUM_NODES;

        pack_edges<<<NQUAD / 256, 256, 0, stream>>>(edge_src, edge_nbr,
                                                    node_weights, packed);
        hist3<<<3 * NSL3, 1024, NPP3 * sizeof(float), stream>>>(packed, rep);
        gemv_reduce<NSL3><<<RED_BLK + 2048, 256, 0, stream>>>(rep, nbr_sum,
                                                              x, theta, h);
        bag_final<<<NUM_BAGS / 4, 256, 0, stream>>>(bags, alpha, h, nbr_sum, out);
    } else if (ws_size >= need8) {
        u32*   packed  = (u32*)d_ws;
        float* rep     = (float*)d_ws + N_EDGES;
        float* nbr_sum = rep + (size_t)NSL8 * NUM_NODES;
        float* h       = nbr_sum + NUM_NODES;

        pack_edges<<<NQUAD / 256, 256, 0, stream>>>(edge_src, edge_nbr,
                                                    node_weights, packed);
        hist_p<<<8 * NSL8, 1024, 0, stream>>>(packed, rep);
        gemv_reduce<NSL8><<<RED_BLK + 2048, 256, 0, stream>>>(rep, nbr_sum,
                                                              x, theta, h);
        bag_final<<<NUM_BAGS / 4, 256, 0, stream>>>(bags, alpha, h, nbr_sum, out);
    } else {
        float* nbr_sum = (float*)d_ws;
        float* h       = nbr_sum + NUM_NODES;
        hipMemsetAsync(nbr_sum, 0, (size_t)NUM_NODES * 4, stream);
        edge_atomic<<<(N_EDGES / 4) / 256, 256, 0, stream>>>(
            edge_src, edge_nbr, node_weights, nbr_sum);
        fixup_nosum<<<(NUM_NODES + 255) / 256, 256, 0, stream>>>(nbr_sum);
        gemv_h<<<2048, 256, 0, stream>>>(x, theta, h);
        bag_final<<<NUM_BAGS / 4, 256, 0, stream>>>(bags, alpha, h, nbr_sum, out);
    }
}